// Round 3
// baseline (209.146 us; speedup 1.0000x reference)
//
#include <hip/hip_runtime.h>

// PointPillarScatter3d on MI355X (gfx950)
// NZ=1, NY=NX=512, C=128, B=4, P=320000.
// Strategy: scatter->gather inversion.
//   hipMemsetAsync: map[B*CELLS] = -1
//   k_scatter_idx:  map[b*CELLS + cell] = point index (cells unique per batch)
//   k_gather:       256-cell tile per block, 4 slices of 32 channels.
//     Phase B: gather 128B row-slices (8 lanes x float4 per cell), transpose into
//              LDS [32ch][260f] via scalar writes (4-way conflict, non-critical).
//     Phase C: per channel, ONE wave instruction stores 1KB contiguous
//              (64 lanes x float4 along x) -> long write bursts, good DRAM row locality.
//   Full output covered -> zeros come from LDS for empty cells, no separate zero pass.

#define NXD 512
#define NYD 512
#define NZD 1
#define CB  128
#define CELLS (NXD * NYD * NZD)   // 262144

#define TILE  256                 // cells per block
#define SLICE 32                  // channels per slice iteration
#define PADF  4                   // pad floats per LDS row (keeps 16B alignment)
#define ROWF  (TILE + PADF)       // 260

__global__ void k_scatter_idx(const int* __restrict__ coords,
                              int* __restrict__ map, int P) {
    int p = blockIdx.x * blockDim.x + threadIdx.x;
    if (p >= P) return;
    int4 c = ((const int4*)coords)[p];      // (b, z, y, x)
    int cell = c.y * (NYD * NXD) + c.z * NXD + c.w;
    map[c.x * CELLS + cell] = p;
}

__global__ __launch_bounds__(256) void k_gather(const float* __restrict__ feat,
                                                const int* __restrict__ map,
                                                float* __restrict__ out) {
    __shared__ int   pidx[TILE];
    __shared__ float ldsT[SLICE * ROWF];    // 33,280 B

    const int t = threadIdx.x;
    const int tiles_per_b = CELLS / TILE;   // 1024
    const int b = blockIdx.x / tiles_per_b;
    const int cell_base = (blockIdx.x % tiles_per_b) * TILE;

    pidx[t] = map[b * CELLS + cell_base + t];
    __syncthreads();

    const int c4    = t & 7;       // float4 column within 32-ch slice (phase B)
    const int cell0 = t >> 3;      // 0..31                          (phase B)
    const int x4    = t & 63;      // float4 index along 256 cells   (phase C)
    const int chr   = t >> 6;      // 0..3                           (phase C)

    // Hoist the 8 point indices this thread serves (same across all slices).
    int idxr[8];
    #pragma unroll
    for (int rr = 0; rr < 8; ++rr) idxr[rr] = pidx[rr * 32 + cell0];

    float* outb = out + (size_t)b * CB * CELLS + cell_base;

    #pragma unroll
    for (int ci = 0; ci < 4; ++ci) {
        // Phase B: 8 independent 128B row-slice loads, transpose into LDS.
        #pragma unroll
        for (int rr = 0; rr < 8; ++rr) {
            const int cell = rr * 32 + cell0;
            const int idx  = idxr[rr];
            float4 v = make_float4(0.f, 0.f, 0.f, 0.f);
            if (idx >= 0)
                v = ((const float4*)feat)[(size_t)idx * (CB / 4) + ci * 8 + c4];
            ldsT[(c4 * 4 + 0) * ROWF + cell] = v.x;
            ldsT[(c4 * 4 + 1) * ROWF + cell] = v.y;
            ldsT[(c4 * 4 + 2) * ROWF + cell] = v.z;
            ldsT[(c4 * 4 + 3) * ROWF + cell] = v.w;
        }
        __syncthreads();

        // Phase C: one 1KB-contiguous wave store per channel.
        #pragma unroll
        for (int cc = 0; cc < 8; ++cc) {
            const int c = cc * 4 + chr;                    // channel within slice
            float4 v = *(const float4*)&ldsT[c * ROWF + x4 * 4];
            *reinterpret_cast<float4*>(outb + (size_t)(ci * SLICE + c) * CELLS + x4 * 4) = v;
        }
        __syncthreads();
    }
}

extern "C" void kernel_launch(void* const* d_in, const int* in_sizes, int n_in,
                              void* d_out, int out_size, void* d_ws, size_t ws_size,
                              hipStream_t stream) {
    const float* feat   = (const float*)d_in[1];
    const int*   coords = (const int*)d_in[2];
    float*       out    = (float*)d_out;
    int*         map    = (int*)d_ws;   // B*CELLS int32 = 4 MB

    const int B = out_size / (CB * CELLS);
    const int P = in_sizes[1] / CB;
    const int n_map = B * CELLS;

    hipMemsetAsync(map, 0xFF, (size_t)n_map * sizeof(int), stream);
    k_scatter_idx<<<(P + 255) / 256, 256, 0, stream>>>(coords, map, P);
    k_gather<<<B * (CELLS / TILE), 256, 0, stream>>>(feat, map, out);
}